// Round 5
// baseline (187.215 us; speedup 1.0000x reference)
//
#include <hip/hip_runtime.h>
#include <hip/hip_bf16.h>

typedef __hip_bfloat16 bf16;
typedef __attribute__((ext_vector_type(8))) short short8;
typedef __attribute__((ext_vector_type(4))) float f32x4;

#define DDIM 1024
#define SEQ  4096
#define NB   4
#define MTOT (NB*SEQ)   // 16384 rows

static __device__ __forceinline__ unsigned short f2bf(float f) {
    __hip_bfloat16 h = __float2bfloat16(f);
    unsigned short u; __builtin_memcpy(&u, &h, 2); return u;
}
static __device__ __forceinline__ float bf2f(unsigned short u) {
    __hip_bfloat16 h; __builtin_memcpy(&h, &u, 2); return __bfloat162float(h);
}

// ------------------------------------------------- pack weights into MFMA-fragment order
// frag(ntile,kt32): lane l holds row n = ntile*16+(l&15), k = kt32*32+(l>>4)*8, 8 elems.
// Packed addr (short8 units): (ntile*32 + kt32)*64 + lane. 2048 frags/matrix = 2 MB.
__global__ __launch_bounds__(256) void pack_w_kernel(
    const float* __restrict__ w1, const float* __restrict__ w2,
    short8* __restrict__ w1p, short8* __restrict__ w2p)
{
    int gid  = blockIdx.x*256 + threadIdx.x;     // grid 1024: 2 x 131072 threads
    int m    = gid >> 17;
    int id   = gid & 131071;
    int frag = id >> 6, lane = id & 63;
    int ntile = frag >> 5, kt32 = frag & 31;
    int n = ntile*16 + (lane & 15);
    int k = kt32*32 + (lane >> 4)*8;
    const float* src = (m ? w2 : w1) + (size_t)n*DDIM + k;
    float4 a = *(const float4*)src;
    float4 b = *(const float4*)(src + 4);
    short8 o;
    o[0]=(short)f2bf(a.x); o[1]=(short)f2bf(a.y); o[2]=(short)f2bf(a.z); o[3]=(short)f2bf(a.w);
    o[4]=(short)f2bf(b.x); o[5]=(short)f2bf(b.y); o[6]=(short)f2bf(b.z); o[7]=(short)f2bf(b.w);
    (m ? w2p : w1p)[id] = o;
}

// ------------------------------------------------------- column sum of x (per batch)
__global__ __launch_bounds__(256) void colsum_partial_kernel(
    const float* __restrict__ x, float* __restrict__ partial)
{
    int d  = blockIdx.x*256 + threadIdx.x;
    int b  = blockIdx.y;
    int sl = blockIdx.z;
    const float* p = x + ((size_t)b*SEQ + (size_t)sl*128)*DDIM + d;
    float s = 0.f;
    #pragma unroll 4
    for (int i = 0; i < 128; ++i) s += p[(size_t)i*DDIM];
    partial[((size_t)sl*NB + b)*DDIM + d] = s;
}

__global__ __launch_bounds__(256) void colsum_reduce_kernel(
    const float* __restrict__ partial, float* __restrict__ xsum)
{
    int d = blockIdx.x*256 + threadIdx.x;
    int b = blockIdx.y;
    float s = 0.f;
    #pragma unroll
    for (int sl = 0; sl < 32; ++sl) s += partial[((size_t)sl*NB + b)*DDIM + d];
    xsum[b*DDIM + d] = s;
}

// ------------------------------------------------------- small matvec: vout = vin @ W^T
__global__ __launch_bounds__(256) void matvec_kernel(
    const float* __restrict__ W, const float* __restrict__ vin, float* __restrict__ vout)
{
    int b = blockIdx.y;
    int g = threadIdx.x >> 4;
    int t = threadIdx.x & 15;
    int e = blockIdx.x*16 + g;
    const float* w = W + (size_t)e*DDIM;
    const float* v = vin + b*DDIM;
    float s = 0.f;
    for (int k = t; k < DDIM; k += 16) s += w[k]*v[k];
    #pragma unroll
    for (int o = 8; o; o >>= 1) s += __shfl_down(s, o, 16);
    if (t == 0) vout[b*DDIM + e] = s;
}

// ------------------------------------------------------- LN1: x1 = LN(x + attnvec) -> bf16
__global__ __launch_bounds__(256) void ln1_kernel(
    const float* __restrict__ x, const float* __restrict__ avec,
    const float* __restrict__ g1, const float* __restrict__ b1,
    unsigned short* __restrict__ x1b)
{
    int row = blockIdx.x;
    int b   = row >> 12;          // row / SEQ
    int tid = threadIdx.x;
    const float4* xr = (const float4*)(x + (size_t)row*DDIM);
    const float4* av = (const float4*)(avec + (size_t)b*DDIM);
    float4 xv = xr[tid], a4 = av[tid];
    float y0 = xv.x+a4.x, y1 = xv.y+a4.y, y2 = xv.z+a4.z, y3 = xv.w+a4.w;
    float s  = y0+y1+y2+y3;
    float ss = y0*y0+y1*y1+y2*y2+y3*y3;
    #pragma unroll
    for (int o = 32; o; o >>= 1) { s += __shfl_down(s,o,64); ss += __shfl_down(ss,o,64); }
    __shared__ float red[8];
    if ((tid&63) == 0) { red[tid>>6] = s; red[4+(tid>>6)] = ss; }
    __syncthreads();
    float St = red[0]+red[1]+red[2]+red[3];
    float Sq = red[4]+red[5]+red[6]+red[7];
    float mu = St*(1.0f/DDIM);
    float rs = rsqrtf(Sq*(1.0f/DDIM) - mu*mu + 1e-5f);
    float4 g4 = ((const float4*)g1)[tid];
    float4 bb = ((const float4*)b1)[tid];
    ushort4 o;
    o.x = f2bf((y0-mu)*rs*g4.x + bb.x);
    o.y = f2bf((y1-mu)*rs*g4.y + bb.y);
    o.z = f2bf((y2-mu)*rs*g4.z + bb.z);
    o.w = f2bf((y3-mu)*rs*g4.w + bb.w);
    *(ushort4*)(x1b + (size_t)row*DDIM + tid*4) = o;
}

// ------------------------------------------------------- 128x128 GEMM, A in LDS / B pre-packed
// C = A @ W^T ; MODE 1: outb = bf16(gelu(C+bias)) ; MODE 2: outf = C + bias + bf16resid
// B fragments stream from L2 (2 MB, fragment-major) into double-buffered registers.
// LDS carries A only (2 x 16 KB). Counted vmcnt(4); 2 barriers/iter; 2 blocks/CU.
template<int MODE>
__global__ __launch_bounds__(256, 2) void gemm_bp_kernel(
    const bf16* __restrict__ A, const short8* __restrict__ Bp,
    const float* __restrict__ bias, const unsigned short* __restrict__ resid,
    unsigned short* __restrict__ outb, float* __restrict__ outf)
{
    constexpr int K = 1024, N = 1024, BK = 64, NT = K / BK;   // 16 K-tiles
    __shared__ __align__(16) bf16 lds[2][128*BK];             // 32 KB, A only
    const int tid  = threadIdx.x;
    const int wave = tid >> 6, lane = tid & 63;

    // T1 bijective XCD swizzle (grid 1024): resident 64 blocks/XCD -> A 2MB + B 2MB fits L2
    int bid = blockIdx.x;
    int swz = (bid & 7) * 128 + (bid >> 3);
    const size_t bm = (size_t)(swz >> 3) * 128;
    const size_t bn = (size_t)(swz & 7) * 128;

    const int wm = wave >> 1;     // 0..1
    const int wn = wave & 1;      // 0..1

    // staging (rule #21): linear LDS dest, inverse-swizzled global source
    const int srow = tid >> 3;
    const int skel = (((tid & 7) ^ ((tid >> 3) & 7)) << 3);

    // fragment reads: logical slot = ks*4 + (lane>>4), phys = slot ^ (row&7)
    const int fr = lane & 15;
    const int fs = lane >> 4;
    int foff[2];
    #pragma unroll
    for (int ks = 0; ks < 2; ++ks)
        foff[ks] = fr*128 + (((ks*4 + fs) ^ (fr & 7)) << 4);

    const bf16* Ab = A + bm * K;
    const int nt0 = (int)(bn >> 4) + wn*4;       // base n-tile for this wave

    auto stageA = [&](int b, int kt) {           // 4 x global_load_lds (16B)
        #pragma unroll
        for (int g = 0; g < 4; ++g) {
            const bf16* gp = Ab + (size_t)(g*32 + srow) * K + kt*BK + skel;
            __builtin_amdgcn_global_load_lds(
                (const __attribute__((address_space(1))) void*)gp,
                (__attribute__((address_space(3))) void*)
                    ((char*)&lds[b][0] + g*4096 + wave*1024),
                16, 0, 0);
        }
    };
    auto loadB = [&](int kt, short8* bf_) {      // 8 coalesced dwordx4 from L2
        #pragma unroll
        for (int kk = 0; kk < 2; ++kk)
            #pragma unroll
            for (int nf = 0; nf < 4; ++nf)
                bf_[kk*4 + nf] = Bp[((nt0 + nf)*32 + kt*2 + kk)*64 + lane];
    };

    f32x4 acc[4][4] = {};
    short8 bcur[8], bnxt[8];

    stageA(0, 0);
    loadB(0, bcur);

    auto iter = [&](int t, short8* bc, short8* bn_) {
        if (t < NT-1) {
            stageA((t+1) & 1, t+1);
            asm volatile("s_waitcnt vmcnt(4)" ::: "memory");  // A(t)+B(t) landed; A(t+1) flies
        } else {
            asm volatile("s_waitcnt vmcnt(0)" ::: "memory");
        }
        __builtin_amdgcn_s_barrier();            // all waves' A(t) in LDS
        if (t < NT-1) {
            loadB(t+1, bn_);                     // prefetch next B under this compute
            asm volatile("" ::: "memory");       // pin issue before the ds_reads below
        }
        const char* LA = (const char*)&lds[t & 1][0] + wm*8192;
        #pragma unroll
        for (int ks = 0; ks < 2; ++ks) {
            short8 af[4];
            #pragma unroll
            for (int m = 0; m < 4; ++m) af[m] = *(const short8*)(LA + m*2048 + foff[ks]);
            __builtin_amdgcn_s_setprio(1);
            #pragma unroll
            for (int m = 0; m < 4; ++m)
                #pragma unroll
                for (int n = 0; n < 4; ++n)
                    acc[m][n] = __builtin_amdgcn_mfma_f32_16x16x32_bf16(
                        af[m], bc[ks*4 + n], acc[m][n], 0, 0, 0);
            __builtin_amdgcn_s_setprio(0);
        }
        __builtin_amdgcn_s_barrier();            // readers done: next iter may overwrite
    };

    #pragma unroll
    for (int t = 0; t < NT; t += 2) {            // parity-named B reg sets (rule #20)
        iter(t,   bcur, bnxt);
        iter(t+1, bnxt, bcur);
    }

    // epilogue (direct stores; round-3 measured write amplification was only ~8%)
    const int crow = (lane >> 4) * 4, ccol = lane & 15;
    #pragma unroll
    for (int n = 0; n < 4; ++n) {
        size_t col = bn + wn*64 + n*16 + ccol;
        float bv = bias[col];
        #pragma unroll
        for (int m = 0; m < 4; ++m) {
            #pragma unroll
            for (int r = 0; r < 4; ++r) {
                size_t row = bm + wm*64 + m*16 + crow + r;
                float v = acc[m][n][r] + bv;
                if (MODE == 1) {
                    float ge = 0.5f*v*(1.0f + erff(v*0.70710678118f));
                    outb[row*(size_t)N + col] = f2bf(ge);
                } else {
                    outf[row*(size_t)N + col] = v + bf2f(resid[row*(size_t)N + col]);
                }
            }
        }
    }
}

// ------------------------------------------------------- LN2 in-place on d_out
__global__ __launch_bounds__(256) void ln2_kernel(
    float* __restrict__ out, const float* __restrict__ g2, const float* __restrict__ b2)
{
    int row = blockIdx.x;
    int tid = threadIdx.x;
    float4* orow = (float4*)(out + (size_t)row*DDIM);
    float4 y = orow[tid];
    float s  = y.x+y.y+y.z+y.w;
    float ss = y.x*y.x+y.y*y.y+y.z*y.z+y.w*y.w;
    #pragma unroll
    for (int o = 32; o; o >>= 1) { s += __shfl_down(s,o,64); ss += __shfl_down(ss,o,64); }
    __shared__ float red[8];
    if ((tid&63) == 0) { red[tid>>6] = s; red[4+(tid>>6)] = ss; }
    __syncthreads();
    float St = red[0]+red[1]+red[2]+red[3];
    float Sq = red[4]+red[5]+red[6]+red[7];
    float mu = St*(1.0f/DDIM);
    float rs = rsqrtf(Sq*(1.0f/DDIM) - mu*mu + 1e-5f);
    float4 g4 = ((const float4*)g2)[tid];
    float4 bb = ((const float4*)b2)[tid];
    float4 n;
    n.x = (y.x-mu)*rs*g4.x + bb.x;
    n.y = (y.y-mu)*rs*g4.y + bb.y;
    n.z = (y.z-mu)*rs*g4.z + bb.z;
    n.w = (y.w-mu)*rs*g4.w + bb.w;
    orow[tid] = n;
}

// ---------------------------------------------------------------- launch
extern "C" void kernel_launch(void* const* d_in, const int* in_sizes, int n_in,
                              void* d_out, int out_size, void* d_ws, size_t ws_size,
                              hipStream_t stream)
{
    const float* x     = (const float*)d_in[0];
    const float* w_qkv = (const float*)d_in[1];
    const float* w_o   = (const float*)d_in[2];
    const float* w1    = (const float*)d_in[3];
    const float* b1    = (const float*)d_in[4];
    const float* w2    = (const float*)d_in[5];
    const float* b2    = (const float*)d_in[6];
    const float* ln1g  = (const float*)d_in[7];
    const float* ln1b  = (const float*)d_in[8];
    const float* ln2g  = (const float*)d_in[9];
    const float* ln2b  = (const float*)d_in[10];
    float* out = (float*)d_out;
    char* ws = (char*)d_ws;

    unsigned short* x1b = (unsigned short*)(ws);               // 32 MB  x1 bf16
    unsigned short* hb  = (unsigned short*)(ws + 33554432);    // 32 MB  h  bf16
    short8* w1p = (short8*)(ws + 67108864);                    // 2 MB packed
    short8* w2p = (short8*)(ws + 69206016);                    // 2 MB packed
    float* partial = (float*)(ws + 71303168);                  // 512 KB
    float* xsum    = (float*)(ws + 71827456);                  // 16 KB
    float* tvec    = (float*)(ws + 71843840);                  // 16 KB
    float* avec    = (float*)(ws + 71860224);                  // 16 KB

    pack_w_kernel<<<dim3(1024), 256, 0, stream>>>(w1, w2, w1p, w2p);
    colsum_partial_kernel<<<dim3(4, NB, 32), 256, 0, stream>>>(x, partial);
    colsum_reduce_kernel<<<dim3(4, NB), 256, 0, stream>>>(partial, xsum);
    matvec_kernel<<<dim3(64, NB), 256, 0, stream>>>(w_qkv + (size_t)2*DDIM*DDIM, xsum, tvec);
    matvec_kernel<<<dim3(64, NB), 256, 0, stream>>>(w_o, tvec, avec);
    ln1_kernel<<<dim3(MTOT), 256, 0, stream>>>(x, avec, ln1g, ln1b, x1b);
    gemm_bp_kernel<1><<<dim3(1024), 256, 0, stream>>>(
        (const bf16*)x1b, w1p, b1, nullptr, hb, nullptr);
    gemm_bp_kernel<2><<<dim3(1024), 256, 0, stream>>>(
        (const bf16*)hb, w2p, b2, x1b, nullptr, out);
    ln2_kernel<<<dim3(MTOT), 256, 0, stream>>>(out, ln2g, ln2b);
}